// Round 4
// baseline (503.253 us; speedup 1.0000x reference)
//
#include <hip/hip_runtime.h>
#include <math.h>

#define NEGF -1000000000.0f
#define EPSF 1e-7f

// B=32, T=256, IN=64, H=128, 4H=512, TOP_K=5

__device__ __forceinline__ float fsigmoid(float x) {
  return 1.0f / (1.0f + __expf(-x));               // overflow -> correct limit
}
__device__ __forceinline__ float ftanh(float x) {
  return 1.0f - 2.0f / (1.0f + __expf(2.0f * x));  // limits +-1: correct
}

// wave64 all-reduce sum via DPP (row_shr 1/2/4/8 + row_bcast 15/31), ~35 cyc.
__device__ __forceinline__ float wave_allsum(float v) {
#if __has_builtin(__builtin_amdgcn_update_dpp) && __has_builtin(__builtin_amdgcn_readlane)
  float f = v;
#define DPPSTEP(ctrl, rmask) { \
    int t = __builtin_amdgcn_update_dpp(0, __builtin_bit_cast(int, f), \
                                        ctrl, rmask, 0xf, true); \
    f += __builtin_bit_cast(float, t); }
  DPPSTEP(0x111, 0xf)   // row_shr:1
  DPPSTEP(0x112, 0xf)   // row_shr:2
  DPPSTEP(0x114, 0xf)   // row_shr:4
  DPPSTEP(0x118, 0xf)   // row_shr:8  -> lane15 of each row has row sum
  DPPSTEP(0x142, 0xa)   // row_bcast:15 into rows 1,3
  DPPSTEP(0x143, 0x8)   // row_bcast:31 into row 3 -> lane 63 = total
#undef DPPSTEP
  return __builtin_bit_cast(float,
      __builtin_amdgcn_readlane(__builtin_bit_cast(int, f), 63));
#else
  for (int off = 1; off < 64; off <<= 1) v += __shfl_xor(v, off, 64);
  return v;
#endif
}

// Kernel 1: xw[b][t][g] = x[b][t] . W_ih[g] + (b_ih[g]+b_hh[g])
// grid (16, 32) = 512 blocks (2/CU -> 8 waves/CU), 256 threads. Thread owns
// TWO gate rows (g, g+256): 32 float4 = 128 VGPR, so the 16 uniform LDS
// x-reads per token are amortized over 128 FMAs (round-3 had 64 -> the
// LDS-issue floor halves). waves_per_eu(2) caps VGPR at 256: no spill.
__global__
__attribute__((amdgpu_flat_work_group_size(256, 256), amdgpu_waves_per_eu(2)))
void xw_kernel(
    const float* __restrict__ x, const float* __restrict__ W_ih,
    const float* __restrict__ b_ih, const float* __restrict__ b_hh,
    float* __restrict__ xw)
{
  const int t0 = blockIdx.x * 16;
  const int b  = blockIdx.y;
  const int g  = threadIdx.x;

  __shared__ float sx[16 * 64];              // 4 KB
  ((float4*)sx)[threadIdx.x] =
      ((const float4*)(x + (size_t)(b * 256 + t0) * 64))[threadIdx.x];

  const float4* wra = (const float4*)(W_ih + (size_t)g * 64);
  const float4* wrb = (const float4*)(W_ih + (size_t)(g + 256) * 64);
  float4 wa0 = wra[0],  wa1 = wra[1],  wa2 = wra[2],  wa3 = wra[3],
         wa4 = wra[4],  wa5 = wra[5],  wa6 = wra[6],  wa7 = wra[7],
         wa8 = wra[8],  wa9 = wra[9],  wa10 = wra[10], wa11 = wra[11],
         wa12 = wra[12], wa13 = wra[13], wa14 = wra[14], wa15 = wra[15];
  float4 wb0 = wrb[0],  wb1 = wrb[1],  wb2 = wrb[2],  wb3 = wrb[3],
         wb4 = wrb[4],  wb5 = wrb[5],  wb6 = wrb[6],  wb7 = wrb[7],
         wb8 = wrb[8],  wb9 = wrb[9],  wb10 = wrb[10], wb11 = wrb[11],
         wb12 = wrb[12], wb13 = wrb[13], wb14 = wrb[14], wb15 = wrb[15];
  const float biasA = b_ih[g] + b_hh[g];
  const float biasB = b_ih[g + 256] + b_hh[g + 256];
  __syncthreads();

  float* dst = xw + (size_t)(b * 256 + t0) * 512 + g;
  for (int tt = 0; tt < 16; ++tt) {
    const float4* xr = (const float4*)(sx + tt * 64);
    float a0 = 0.0f, a1 = 0.0f, a2 = 0.0f, a3 = 0.0f;
    float c0 = 0.0f, c1 = 0.0f, c2 = 0.0f, c3 = 0.0f;
#define XSTEP(j) { float4 hv = xr[j]; \
    a0 = fmaf(wa##j.x, hv.x, a0); a1 = fmaf(wa##j.y, hv.y, a1); \
    a2 = fmaf(wa##j.z, hv.z, a2); a3 = fmaf(wa##j.w, hv.w, a3); \
    c0 = fmaf(wb##j.x, hv.x, c0); c1 = fmaf(wb##j.y, hv.y, c1); \
    c2 = fmaf(wb##j.z, hv.z, c2); c3 = fmaf(wb##j.w, hv.w, c3); }
    XSTEP(0) XSTEP(1) XSTEP(2) XSTEP(3) XSTEP(4) XSTEP(5) XSTEP(6) XSTEP(7)
    XSTEP(8) XSTEP(9) XSTEP(10) XSTEP(11) XSTEP(12) XSTEP(13) XSTEP(14) XSTEP(15)
#undef XSTEP
    dst[(size_t)tt * 512]       = (a0 + a1) + (a2 + a3) + biasA;
    dst[(size_t)tt * 512 + 256] = (c0 + c1) + (c2 + c3) + biasB;
  }
}

// Kernel 2: full recurrence, one block per batch element, 256 threads
// (4 waves, 1 wave/SIMD). Thread (q = tid>>6, l = tid&63) owns EIGHT gates
// 8l..8l+7 on K-chunk q (8 gates x 8 float4 = 256 weight VGPRs; cap 512 at
// waves_per_eu(1,1); m08: no spill through 450). vs round 3's 16 waves:
// Phase-A LDS h-broadcast reads drop 128 -> 32 instrs/step (the h row was
// re-read by every wave; the LDS pipe at ~12cyc/b128 was the ~1600cyc/step
// bottleneck). sh_part layout [q][gate] and Phase B/C/D are UNCHANGED.
//
// DELTA CANCELLATION (unchanged):
//   s[t] = a + d[t]; delta = a + top5(d)[4] + EPS  =>  w[t] = d[t]-t5v4-EPS
//   independent of a. Sparse attention = 4 register-indexed LDS row gathers
//   whose addresses are known from the PREVIOUS step (prefetched before S1).
//   Raw-score path (rem<=5) kept as a 5-step special case.
__global__
__attribute__((amdgpu_flat_work_group_size(256, 256), amdgpu_waves_per_eu(1, 1)))
void lstm_attn(
    const float* __restrict__ xw, const float* __restrict__ W_hh,
    const float* __restrict__ w_t, float* __restrict__ out)
{
  const int b   = blockIdx.x;
  const int tid = threadIdx.x;
  const int l   = tid & 63;       // lane
  const int q   = tid >> 6;       // K-chunk 0..3 == wave id
  const int gb  = l << 3;         // gate octet base: gates gb..gb+7

  __shared__ float ho[257 * 128];     // fp32 h history (131584 B), row i = h after step i-1
  __shared__ float sh_part[4 * 512];  // gate partials [q][gate] (8 KB)
  __shared__ float sh_d[8];           // d[t] cache, only needed for t<5

  // one-time weight load: 8 gates x 8 float4 = 64 named float4 = 256 VGPRs
#define LOADW(g) \
  const float4* pw##g = (const float4*)(W_hh + (size_t)(gb + g) * 128 + (q << 5)); \
  float4 w##g##_0 = pw##g[0], w##g##_1 = pw##g[1], w##g##_2 = pw##g[2], \
         w##g##_3 = pw##g[3], w##g##_4 = pw##g[4], w##g##_5 = pw##g[5], \
         w##g##_6 = pw##g[6], w##g##_7 = pw##g[7];
  LOADW(0) LOADW(1) LOADW(2) LOADW(3) LOADW(4) LOADW(5) LOADW(6) LOADW(7)
#undef LOADW

  // wave0 per-lane persistent state (h elements j0=2l, j1=2l+1)
  const int j0 = 2 * l, j1 = 2 * l + 1;
  float c0 = 0.0f, c1 = 0.0f;
  float wa0 = 0.0f, wa1 = 0.0f, wb0 = 0.0f, wb1 = 0.0f;
  // running top-5 of d with indices (replicated identically in all wave0 lanes)
  float t5v0 = 0.0f, t5v1 = NEGF, t5v2 = NEGF, t5v3 = NEGF, t5v4 = NEGF;
  int   t5i0 = 0, t5i1 = 0, t5i2 = 0, t5i3 = 0;
  // precomputed (at end of step i-1) normalized gather weights + LDS offsets
  float gn0 = 0.0f, gn1 = 0.0f, gn2 = 0.0f, gn3 = 0.0f;
  int   ofs0 = 0, ofs1 = 0, ofs2 = 0, ofs3 = 0;

  if (q == 0) {
    wa0 = w_t[j0];       wa1 = w_t[j1];
    wb0 = w_t[128 + j0]; wb1 = w_t[128 + j1];
    *(float2*)(ho + j0) = make_float2(0.0f, 0.0f);   // h(-1) = 0 (row 0)
  }
  if (tid == 0) sh_d[0] = 0.0f;
  __syncthreads();

  const float* xwb = xw + (size_t)b * 256 * 512;
  float4 xc0 = make_float4(0.f, 0.f, 0.f, 0.f);
  float4 xc1 = make_float4(0.f, 0.f, 0.f, 0.f);
  if (q == 0) {
    xc0 = ((const float4*)(xwb + gb))[0];
    xc1 = ((const float4*)(xwb + gb))[1];
  }

  for (int i = 0; i < 256; ++i) {
    const int rem = i + 1;
    float hn0 = 0.0f, hn1 = 0.0f;

    // ---- Phase A: 8 gate-partials, 256 FMAs from resident fp32 weights ----
    float A0x = xc0.x, A0y = 0.0f, A1x = xc0.y, A1y = 0.0f;
    float A2x = xc0.z, A2y = 0.0f, A3x = xc0.w, A3y = 0.0f;
    float A4x = xc1.x, A4y = 0.0f, A5x = xc1.y, A5y = 0.0f;
    float A6x = xc1.z, A6y = 0.0f, A7x = xc1.w, A7y = 0.0f;
    if (q == 0 && i < 255) {          // prefetch next step's xw (8 gates)
      xc0 = ((const float4*)(xwb + (size_t)(i + 1) * 512 + gb))[0];
      xc1 = ((const float4*)(xwb + (size_t)(i + 1) * 512 + gb))[1];
    }
    const float4* hh4 = (const float4*)(ho + i * 128 + (q << 5));
#define FGA(g, kk) \
    A##g##x = fmaf(w##g##_##kk.x, hv.x, A##g##x); \
    A##g##y = fmaf(w##g##_##kk.y, hv.y, A##g##y); \
    A##g##x = fmaf(w##g##_##kk.z, hv.z, A##g##x); \
    A##g##y = fmaf(w##g##_##kk.w, hv.w, A##g##y);
#define KSTEP(kk) { float4 hv = hh4[kk]; \
    FGA(0, kk) FGA(1, kk) FGA(2, kk) FGA(3, kk) \
    FGA(4, kk) FGA(5, kk) FGA(6, kk) FGA(7, kk) }
    KSTEP(0) KSTEP(1) KSTEP(2) KSTEP(3) KSTEP(4) KSTEP(5) KSTEP(6) KSTEP(7)
#undef KSTEP
#undef FGA
    {
      float4* sp4 = (float4*)(sh_part + (q << 9) + (l << 3));
      sp4[0] = make_float4(A0x + A0y, A1x + A1y, A2x + A2y, A3x + A3y);
      sp4[1] = make_float4(A4x + A4y, A5x + A5y, A6x + A6y, A7x + A7y);
    }

    // gather prefetch: addresses known from previous step's top-5; ho rows
    // are append-only so reading before the barrier is race-free.
    float2 hv0, hv1, hv2, hv3;
    if (q == 0 && i >= 5) {
      hv0 = *(const float2*)(ho + ofs0);
      hv1 = *(const float2*)(ho + ofs1);
      hv2 = *(const float2*)(ho + ofs2);
      hv3 = *(const float2*)(ho + ofs3);
    }
    __syncthreads();                                      // S1

    if (q == 0) {
      // ---- Phase B: LSTM cell (2 elements/lane) ----
#define GSUM(base) ({ \
      float2 x0 = ((const float2*)(sh_part        + (base)))[l]; \
      float2 x1 = ((const float2*)(sh_part +  512 + (base)))[l]; \
      float2 x2 = ((const float2*)(sh_part + 1024 + (base)))[l]; \
      float2 x3 = ((const float2*)(sh_part + 1536 + (base)))[l]; \
      float2 r; r.x = (x0.x + x1.x) + (x2.x + x3.x); \
      r.y = (x0.y + x1.y) + (x2.y + x3.y); r; })
      float2 Pi = GSUM(0), Pf = GSUM(128), Pg = GSUM(256), Po = GSUM(384);
#undef GSUM
      c0 = fsigmoid(Pf.x) * c0 + fsigmoid(Pi.x) * ftanh(Pg.x);
      c1 = fsigmoid(Pf.y) * c1 + fsigmoid(Pi.y) * ftanh(Pg.y);
      float hc0 = fsigmoid(Po.x) * ftanh(c0);
      float hc1 = fsigmoid(Po.y) * ftanh(c1);

      float at0, at1;
      if (i >= 5) {
        // ---- sparse attention: 4 pre-fetched rows, register weights ----
        at0 = gn0 * hv0.x;            at1 = gn0 * hv0.y;
        at0 = fmaf(gn1, hv1.x, at0);  at1 = fmaf(gn1, hv1.y, at1);
        at0 = fmaf(gn2, hv2.x, at0);  at1 = fmaf(gn2, hv2.y, at1);
        at0 = fmaf(gn3, hv3.x, at0);  at1 = fmaf(gn3, hv3.y, at1);
      } else {
        // ---- rem<=5: attn weights are RAW scores s = a + d[t], no norm ----
        float a = wave_allsum(ftanh(hc0) * wa0 + ftanh(hc1) * wa1);
        at0 = 0.0f; at1 = 0.0f;
        for (int t = 0; t <= i; ++t) {
          float s = a + sh_d[t];
          float2 hv = *(const float2*)(ho + t * 128 + j0);
          at0 = fmaf(s, hv.x, at0);
          at1 = fmaf(s, hv.y, at1);
        }
      }
      hn0 = hc0 + at0; hn1 = hc1 + at1;
      *(float2*)(ho + rem * 128 + j0) = make_float2(hn0, hn1);
      if (i == 255) {
        out[b * 128 + j0] = at0; out[b * 128 + j1] = at1;   // attn_c
        // attn_w: zero except at the <=4 above-threshold top-5 indices
        #pragma unroll
        for (int m = 0; m < 4; ++m) {
          int t = l + 64 * m;
          float val = 0.0f;
          if (t == t5i0) val = gn0;
          if (t == t5i1) val = gn1;
          if (t == t5i2) val = gn2;
          if (t == t5i3) val = gn3;
          out[4096 + b * 256 + t] = val;
        }
      }
    }
    __syncthreads();                                      // S2

    // ---- tail (off critical path: overlaps other waves' next Phase A) ----
    if (q == 0 && i < 255) {
      float dn = wave_allsum(ftanh(hn0) * wb0 + ftanh(hn1) * wb1);
      if (l == 0 && i < 4) sh_d[rem] = dn;   // only raw-score steps read it
      // replicated top-5 (value,index) insert — identical in every lane
      float v = dn; int vi = rem;
      if (v > t5v0) { float tv = t5v0; int ti = t5i0; t5v0 = v; t5i0 = vi; v = tv; vi = ti; }
      if (v > t5v1) { float tv = t5v1; int ti = t5i1; t5v1 = v; t5i1 = vi; v = tv; vi = ti; }
      if (v > t5v2) { float tv = t5v2; int ti = t5i2; t5v2 = v; t5i2 = vi; v = tv; vi = ti; }
      if (v > t5v3) { float tv = t5v3; int ti = t5i3; t5v3 = v; t5i3 = vi; v = tv; vi = ti; }
      if (v > t5v4) { t5v4 = v; }
      // next step's normalized gather weights + offsets (delta cancellation:
      // w[t] = d[t] - t5v4 - EPS, nonzero only among top-4)
      float g0 = fmaxf(t5v0 - t5v4 - EPSF, 0.0f);
      float g1 = fmaxf(t5v1 - t5v4 - EPSF, 0.0f);
      float g2 = fmaxf(t5v2 - t5v4 - EPSF, 0.0f);
      float g3 = fmaxf(t5v3 - t5v4 - EPSF, 0.0f);
      float inv = 1.0f / (((g0 + g1) + (g2 + g3)) + EPSF);
      gn0 = g0 * inv; gn1 = g1 * inv; gn2 = g2 * inv; gn3 = g3 * inv;
      ofs0 = (t5i0 << 7) + j0; ofs1 = (t5i1 << 7) + j0;
      ofs2 = (t5i2 << 7) + j0; ofs3 = (t5i3 << 7) + j0;
    }
  }
}

extern "C" void kernel_launch(void* const* d_in, const int* in_sizes, int n_in,
                              void* d_out, int out_size, void* d_ws, size_t ws_size,
                              hipStream_t stream) {
  const float* x    = (const float*)d_in[0];  // (32,256,64)
  const float* W_ih = (const float*)d_in[1];  // (512,64)
  const float* W_hh = (const float*)d_in[2];  // (512,128)
  const float* b_ih = (const float*)d_in[3];  // (512,)
  const float* b_hh = (const float*)d_in[4];  // (512,)
  const float* w_t  = (const float*)d_in[5];  // (256,1)
  float* out = (float*)d_out;                 // [0:4096) attn_c, [4096:12288) attn_w

  float* xw = (float*)d_ws;                   // 32*256*512 fp32 = 16 MB

  xw_kernel<<<dim3(16, 32), 256, 0, stream>>>(x, W_ih, b_ih, b_hh, xw);
  lstm_attn<<<dim3(32), 256, 0, stream>>>(xw, W_hh, w_t, out);
}

// Round 5
// 415.294 us; speedup vs baseline: 1.2118x; 1.2118x over previous
//
#include <hip/hip_runtime.h>
#include <math.h>

#define NEGF -1000000000.0f
#define EPSF 1e-7f

// B=32, T=256, IN=64, H=128, 4H=512, TOP_K=5

// Raw barrier: LDS-only drain (s_waitcnt lgkmcnt(0)) + s_barrier.
// __syncthreads() would emit s_waitcnt vmcnt(0) lgkmcnt(0) and drain the
// in-flight xw global prefetch on the critical path EVERY step (2 barriers
// x 200-900cyc L2/HBM latency = the ~2000cyc/step round-1 mystery gap).
// The only cross-wave dependencies through the barriers are LDS (sh_part,
// ho); the global loads are consumed by their issuing wave only, so the
// compiler's automatic vmcnt-before-use covers them.
#define RAWBAR() asm volatile("s_waitcnt lgkmcnt(0)\n\ts_barrier" ::: "memory")

__device__ __forceinline__ float fsigmoid(float x) {
  return 1.0f / (1.0f + __expf(-x));               // overflow -> correct limit
}
__device__ __forceinline__ float ftanh(float x) {
  return 1.0f - 2.0f / (1.0f + __expf(2.0f * x));  // limits +-1: correct
}

// wave64 all-reduce sum via DPP (row_shr 1/2/4/8 + row_bcast 15/31), ~35 cyc.
__device__ __forceinline__ float wave_allsum(float v) {
#if __has_builtin(__builtin_amdgcn_update_dpp) && __has_builtin(__builtin_amdgcn_readlane)
  float f = v;
#define DPPSTEP(ctrl, rmask) { \
    int t = __builtin_amdgcn_update_dpp(0, __builtin_bit_cast(int, f), \
                                        ctrl, rmask, 0xf, true); \
    f += __builtin_bit_cast(float, t); }
  DPPSTEP(0x111, 0xf)   // row_shr:1
  DPPSTEP(0x112, 0xf)   // row_shr:2
  DPPSTEP(0x114, 0xf)   // row_shr:4
  DPPSTEP(0x118, 0xf)   // row_shr:8  -> lane15 of each row has row sum
  DPPSTEP(0x142, 0xa)   // row_bcast:15 into rows 1,3
  DPPSTEP(0x143, 0x8)   // row_bcast:31 into row 3 -> lane 63 = total
#undef DPPSTEP
  return __builtin_bit_cast(float,
      __builtin_amdgcn_readlane(__builtin_bit_cast(int, f), 63));
#else
  for (int off = 1; off < 64; off <<= 1) v += __shfl_xor(v, off, 64);
  return v;
#endif
}

// Kernel 1: xw[b][t][g] = x[b][t] . W_ih[g] + (b_ih[g]+b_hh[g])
// EXACT round-3 version (its share of the total was 82us there).
__global__ __launch_bounds__(512) void xw_kernel(
    const float* __restrict__ x, const float* __restrict__ W_ih,
    const float* __restrict__ b_ih, const float* __restrict__ b_hh,
    float* __restrict__ xw)
{
  const int t0 = blockIdx.x * 32;
  const int b  = blockIdx.y;
  const int g  = threadIdx.x;

  __shared__ float sx[32 * 64];              // 8 KB
  ((float4*)sx)[threadIdx.x] =
      ((const float4*)(x + (size_t)(b * 256 + t0) * 64))[threadIdx.x];

  const float4* wr = (const float4*)(W_ih + (size_t)g * 64);
  float4 w0 = wr[0],  w1 = wr[1],  w2 = wr[2],  w3 = wr[3],
         w4 = wr[4],  w5 = wr[5],  w6 = wr[6],  w7 = wr[7],
         w8 = wr[8],  w9 = wr[9],  w10 = wr[10], w11 = wr[11],
         w12 = wr[12], w13 = wr[13], w14 = wr[14], w15 = wr[15];
  const float bias = b_ih[g] + b_hh[g];
  __syncthreads();

  float* dst = xw + (size_t)(b * 256 + t0) * 512 + g;
  for (int tt = 0; tt < 32; ++tt) {
    const float4* xr = (const float4*)(sx + tt * 64);
    float a0 = 0.0f, a1 = 0.0f, a2 = 0.0f, a3 = 0.0f;
#define XSTEP(j) { float4 hv = xr[j]; \
    a0 = fmaf(w##j.x, hv.x, a0); a1 = fmaf(w##j.y, hv.y, a1); \
    a2 = fmaf(w##j.z, hv.z, a2); a3 = fmaf(w##j.w, hv.w, a3); }
    XSTEP(0) XSTEP(1) XSTEP(2) XSTEP(3) XSTEP(4) XSTEP(5) XSTEP(6) XSTEP(7)
    XSTEP(8) XSTEP(9) XSTEP(10) XSTEP(11) XSTEP(12) XSTEP(13) XSTEP(14) XSTEP(15)
#undef XSTEP
    dst[(size_t)tt * 512] = (a0 + a1) + (a2 + a3) + bias;
  }
}

// Kernel 2: full recurrence, one block per batch element, 1024 threads.
// Round-1 structure (measured 330us; round-4's 4-wave/256-VGPR variant hit
// AGPR shuffling at VGPR_Count=184 + zero TLP -> 391us, reverted) with ONE
// change: S1/S2 are raw s_barrier + lgkmcnt-only waits (see RAWBAR above),
// so the q==0 waves' xw prefetch stays in flight across both barriers.
//
// DELTA CANCELLATION (unchanged):
//   s[t] = a + d[t]; delta = a + top5(d)[4] + EPS  =>  w[t] = d[t]-t5v4-EPS
//   independent of a. Sparse attention = 4 register-indexed LDS row gathers
//   whose addresses are known from the PREVIOUS step (prefetched before S1).
//   Raw-score path (rem<=5) kept as a 5-step special case.
__global__
__attribute__((amdgpu_flat_work_group_size(1024, 1024), amdgpu_waves_per_eu(4, 4)))
void lstm_attn(
    const float* __restrict__ xw, const float* __restrict__ W_hh,
    const float* __restrict__ w_t, float* __restrict__ out)
{
  const int b   = blockIdx.x;
  const int tid = threadIdx.x;
  const int l   = tid & 63;       // lane
  const int wid = tid >> 6;
  const int p   = tid & 255;      // gate-pair id
  const int q   = tid >> 8;       // K-chunk 0..3 (wave-uniform)
  const int gA  = p;
  const int gB  = p + 256;

  __shared__ float ho[257 * 128];     // fp32 h history (131584 B), row i = h after step i-1
  __shared__ float sh_part[4 * 512];  // gate partials [q][gate] (8 KB)
  __shared__ float sh_d[8];           // d[t] cache, only needed for t<5

  // one-time weight load: 16 named float4 = 64 regs
  const float4* pA = (const float4*)(W_hh + (size_t)gA * 128 + (q << 5));
  const float4* pB = (const float4*)(W_hh + (size_t)gB * 128 + (q << 5));
  float4 wA0 = pA[0], wA1 = pA[1], wA2 = pA[2], wA3 = pA[3],
         wA4 = pA[4], wA5 = pA[5], wA6 = pA[6], wA7 = pA[7];
  float4 wB0 = pB[0], wB1 = pB[1], wB2 = pB[2], wB3 = pB[3],
         wB4 = pB[4], wB5 = pB[5], wB6 = pB[6], wB7 = pB[7];

  // wave0 per-lane persistent state (h elements j0=2l, j1=2l+1)
  const int j0 = 2 * l, j1 = 2 * l + 1;
  float c0 = 0.0f, c1 = 0.0f;
  float wa0 = 0.0f, wa1 = 0.0f, wb0 = 0.0f, wb1 = 0.0f;
  // running top-5 of d with indices (replicated identically in all wave0 lanes)
  float t5v0 = 0.0f, t5v1 = NEGF, t5v2 = NEGF, t5v3 = NEGF, t5v4 = NEGF;
  int   t5i0 = 0, t5i1 = 0, t5i2 = 0, t5i3 = 0;
  // precomputed (at end of step i-1) normalized gather weights + LDS offsets
  float gn0 = 0.0f, gn1 = 0.0f, gn2 = 0.0f, gn3 = 0.0f;
  int   ofs0 = 0, ofs1 = 0, ofs2 = 0, ofs3 = 0;

  if (wid == 0) {
    wa0 = w_t[j0];       wa1 = w_t[j1];
    wb0 = w_t[128 + j0]; wb1 = w_t[128 + j1];
    *(float2*)(ho + j0) = make_float2(0.0f, 0.0f);   // h(-1) = 0 (row 0)
    __builtin_amdgcn_s_setprio(1);   // wave0 is always the barrier straggler
  }
  if (tid == 0) sh_d[0] = 0.0f;
  __syncthreads();   // one-time full sync (drains w_t loads too)

  const float* xwb = xw + (size_t)b * 256 * 512;
  float xcurA = 0.0f, xcurB = 0.0f;
  if (q == 0) { xcurA = xwb[gA]; xcurB = xwb[gB]; }

  for (int i = 0; i < 256; ++i) {
    const int rem = i + 1;
    float hn0 = 0.0f, hn1 = 0.0f;

    // ---- Phase A: gate partials (64 FMAs from resident fp32 weights) ----
    float aA0 = xcurA, aA1 = 0.0f, aB0 = xcurB, aB1 = 0.0f;
    if (q == 0 && i < 255) {          // prefetch next step's xw (stays in
      xcurA = xwb[(size_t)(i + 1) * 512 + gA];   // flight across RAWBARs)
      xcurB = xwb[(size_t)(i + 1) * 512 + gB];
    }
    const float4* hh4 = (const float4*)(ho + i * 128 + (q << 5));
#define LSTEP(j) { float4 hv = hh4[j]; \
    aA0 = fmaf(wA##j.x, hv.x, aA0); aA1 = fmaf(wA##j.y, hv.y, aA1); \
    aA0 = fmaf(wA##j.z, hv.z, aA0); aA1 = fmaf(wA##j.w, hv.w, aA1); \
    aB0 = fmaf(wB##j.x, hv.x, aB0); aB1 = fmaf(wB##j.y, hv.y, aB1); \
    aB0 = fmaf(wB##j.z, hv.z, aB0); aB1 = fmaf(wB##j.w, hv.w, aB1); }
    LSTEP(0) LSTEP(1) LSTEP(2) LSTEP(3) LSTEP(4) LSTEP(5) LSTEP(6) LSTEP(7)
#undef LSTEP
    sh_part[(q << 9) + gA] = aA0 + aA1;
    sh_part[(q << 9) + gB] = aB0 + aB1;

    // gather prefetch: addresses known from previous step's top-5; ho rows
    // are append-only so reading before the barrier is race-free.
    float2 hv0, hv1, hv2, hv3;
    if (wid == 0 && i >= 5) {
      hv0 = *(const float2*)(ho + ofs0);
      hv1 = *(const float2*)(ho + ofs1);
      hv2 = *(const float2*)(ho + ofs2);
      hv3 = *(const float2*)(ho + ofs3);
    }
    RAWBAR();                                             // S1

    if (wid == 0) {
      // ---- Phase B: LSTM cell (2 elements/lane) ----
#define GSUM(base) ({ \
      float2 x0 = ((const float2*)(sh_part        + (base)))[l]; \
      float2 x1 = ((const float2*)(sh_part +  512 + (base)))[l]; \
      float2 x2 = ((const float2*)(sh_part + 1024 + (base)))[l]; \
      float2 x3 = ((const float2*)(sh_part + 1536 + (base)))[l]; \
      float2 r; r.x = (x0.x + x1.x) + (x2.x + x3.x); \
      r.y = (x0.y + x1.y) + (x2.y + x3.y); r; })
      float2 Pi = GSUM(0), Pf = GSUM(128), Pg = GSUM(256), Po = GSUM(384);
#undef GSUM
      c0 = fsigmoid(Pf.x) * c0 + fsigmoid(Pi.x) * ftanh(Pg.x);
      c1 = fsigmoid(Pf.y) * c1 + fsigmoid(Pi.y) * ftanh(Pg.y);
      float hc0 = fsigmoid(Po.x) * ftanh(c0);
      float hc1 = fsigmoid(Po.y) * ftanh(c1);

      float at0, at1;
      if (i >= 5) {
        // ---- sparse attention: 4 pre-fetched rows, register weights ----
        at0 = gn0 * hv0.x;            at1 = gn0 * hv0.y;
        at0 = fmaf(gn1, hv1.x, at0);  at1 = fmaf(gn1, hv1.y, at1);
        at0 = fmaf(gn2, hv2.x, at0);  at1 = fmaf(gn2, hv2.y, at1);
        at0 = fmaf(gn3, hv3.x, at0);  at1 = fmaf(gn3, hv3.y, at1);
      } else {
        // ---- rem<=5: attn weights are RAW scores s = a + d[t], no norm ----
        float a = wave_allsum(ftanh(hc0) * wa0 + ftanh(hc1) * wa1);
        at0 = 0.0f; at1 = 0.0f;
        for (int t = 0; t <= i; ++t) {
          float s = a + sh_d[t];
          float2 hv = *(const float2*)(ho + t * 128 + j0);
          at0 = fmaf(s, hv.x, at0);
          at1 = fmaf(s, hv.y, at1);
        }
      }
      hn0 = hc0 + at0; hn1 = hc1 + at1;
      *(float2*)(ho + rem * 128 + j0) = make_float2(hn0, hn1);
      if (i == 255) {
        out[b * 128 + j0] = at0; out[b * 128 + j1] = at1;   // attn_c
        // attn_w: zero except at the <=4 above-threshold top-5 indices
        #pragma unroll
        for (int m = 0; m < 4; ++m) {
          int t = l + 64 * m;
          float val = 0.0f;
          if (t == t5i0) val = gn0;
          if (t == t5i1) val = gn1;
          if (t == t5i2) val = gn2;
          if (t == t5i3) val = gn3;
          out[4096 + b * 256 + t] = val;
        }
      }
    }
    RAWBAR();                                             // S2

    // ---- tail (off critical path: overlaps other waves' next Phase A) ----
    if (wid == 0 && i < 255) {
      float dn = wave_allsum(ftanh(hn0) * wb0 + ftanh(hn1) * wb1);
      if (l == 0 && i < 4) sh_d[rem] = dn;   // only raw-score steps read it
      // replicated top-5 (value,index) insert — identical in every lane
      float v = dn; int vi = rem;
      if (v > t5v0) { float tv = t5v0; int ti = t5i0; t5v0 = v; t5i0 = vi; v = tv; vi = ti; }
      if (v > t5v1) { float tv = t5v1; int ti = t5i1; t5v1 = v; t5i1 = vi; v = tv; vi = ti; }
      if (v > t5v2) { float tv = t5v2; int ti = t5i2; t5v2 = v; t5i2 = vi; v = tv; vi = ti; }
      if (v > t5v3) { float tv = t5v3; int ti = t5i3; t5v3 = v; t5i3 = vi; v = tv; vi = ti; }
      if (v > t5v4) { t5v4 = v; }
      // next step's normalized gather weights + offsets (delta cancellation:
      // w[t] = d[t] - t5v4 - EPS, nonzero only among top-4)
      float g0 = fmaxf(t5v0 - t5v4 - EPSF, 0.0f);
      float g1 = fmaxf(t5v1 - t5v4 - EPSF, 0.0f);
      float g2 = fmaxf(t5v2 - t5v4 - EPSF, 0.0f);
      float g3 = fmaxf(t5v3 - t5v4 - EPSF, 0.0f);
      float inv = 1.0f / (((g0 + g1) + (g2 + g3)) + EPSF);
      gn0 = g0 * inv; gn1 = g1 * inv; gn2 = g2 * inv; gn3 = g3 * inv;
      ofs0 = (t5i0 << 7) + j0; ofs1 = (t5i1 << 7) + j0;
      ofs2 = (t5i2 << 7) + j0; ofs3 = (t5i3 << 7) + j0;
    }
  }
}

extern "C" void kernel_launch(void* const* d_in, const int* in_sizes, int n_in,
                              void* d_out, int out_size, void* d_ws, size_t ws_size,
                              hipStream_t stream) {
  const float* x    = (const float*)d_in[0];  // (32,256,64)
  const float* W_ih = (const float*)d_in[1];  // (512,64)
  const float* W_hh = (const float*)d_in[2];  // (512,128)
  const float* b_ih = (const float*)d_in[3];  // (512,)
  const float* b_hh = (const float*)d_in[4];  // (512,)
  const float* w_t  = (const float*)d_in[5];  // (256,1)
  float* out = (float*)d_out;                 // [0:4096) attn_c, [4096:12288) attn_w

  float* xw = (float*)d_ws;                   // 32*256*512 fp32 = 16 MB

  xw_kernel<<<dim3(8, 32), 512, 0, stream>>>(x, W_ih, b_ih, b_hh, xw);
  lstm_attn<<<dim3(32), 1024, 0, stream>>>(xw, W_hh, w_t, out);
}